// Round 1
// baseline (8703.886 us; speedup 1.0000x reference)
//
#include <hip/hip_runtime.h>
#include <math.h>

// Problem constants (fixed by reference)
#define BATCH 2
#define SEQ   2048
#define DMODEL 2048
#define NHEADS 16
#define HDIM  128
#define MROWS (BATCH * SEQ)   // 4096

// ---------------------------------------------------------------------------
// GEMM: C[M,N] = A[M,K] @ W[K,N] + bias[N]   (fp32, 64x64x16 LDS tiles)
// ---------------------------------------------------------------------------
constexpr int BM = 64, BN = 64, BK = 16;

__global__ __launch_bounds__(256) void gemm_bias_kernel(
    const float* __restrict__ A, const float* __restrict__ W,
    const float* __restrict__ bias, float* __restrict__ C,
    int M, int N, int K)
{
    // +4 pad keeps 16B alignment for ds_read_b128 AND breaks bank conflicts
    __shared__ __align__(16) float As[BK][BM + 4];
    __shared__ __align__(16) float Ws[BK][BN];

    const int tid = threadIdx.x;
    const int tx  = tid & 15;   // n-direction, 0..15
    const int ty  = tid >> 4;   // m-direction, 0..15
    const int bm  = blockIdx.y * BM;
    const int bn  = blockIdx.x * BN;

    // A-tile loader: one float4 per thread. row 0..63, col4 in {0,4,8,12}
    const int a_row = tid >> 2;
    const int a_c4  = (tid & 3) << 2;
    // W-tile loader: one float4 per thread. row 0..15, col4 in {0..60}
    const int w_row = tid >> 4;
    const int w_c4  = (tid & 15) << 2;

    float acc[4][4] = {};

    for (int k0 = 0; k0 < K; k0 += BK) {
        const float4 av = *(const float4*)(A + (size_t)(bm + a_row) * K + k0 + a_c4);
        As[a_c4 + 0][a_row] = av.x;
        As[a_c4 + 1][a_row] = av.y;
        As[a_c4 + 2][a_row] = av.z;
        As[a_c4 + 3][a_row] = av.w;
        *(float4*)(&Ws[w_row][w_c4]) =
            *(const float4*)(W + (size_t)(k0 + w_row) * N + bn + w_c4);
        __syncthreads();

        #pragma unroll
        for (int kk = 0; kk < BK; ++kk) {
            float a[4], w[4];
            #pragma unroll
            for (int i = 0; i < 4; ++i) a[i] = As[kk][ty * 4 + i];
            #pragma unroll
            for (int i = 0; i < 4; ++i) w[i] = Ws[kk][tx * 4 + i];
            #pragma unroll
            for (int i = 0; i < 4; ++i)
                #pragma unroll
                for (int j = 0; j < 4; ++j)
                    acc[i][j] += a[i] * w[j];
        }
        __syncthreads();
    }

    #pragma unroll
    for (int i = 0; i < 4; ++i) {
        const int row = bm + ty * 4 + i;
        #pragma unroll
        for (int j = 0; j < 4; ++j) {
            const int col = bn + tx * 4 + j;
            C[(size_t)row * N + col] = acc[i][j] + bias[col];
        }
    }
}

// ---------------------------------------------------------------------------
// Attention: flash-style online softmax with ALiBi + causal mask.
// One wave handles 4 consecutive query rows of one (b,h); block = 4 waves =
// 16 rows. Q is read from QO and the output O overwrites the same rows
// (safe: each wave reads only its own rows into registers first).
// Scores kept in log2 domain: q pre-scaled by (1/sqrt(hd))*log2(e).
// ---------------------------------------------------------------------------
__global__ __launch_bounds__(256) void attn_kernel(
    float* __restrict__ QO, const float* __restrict__ K,
    const float* __restrict__ V)
{
    const int lane = threadIdx.x & 63;
    const int wave = threadIdx.x >> 6;
    const int h = blockIdx.y;
    const int b = blockIdx.z;
    const int q0 = blockIdx.x * 16 + wave * 4;   // rows q0..q0+3

    const size_t headbase = ((size_t)b * SEQ) * DMODEL + (size_t)h * HDIM;

    // (1/sqrt(128)) * log2(e)
    const float qscale = 0.08838834764831845f * 1.4426950408889634f;
    const float slope2 = exp2f(-0.5f * (float)(h + 1)) * 1.4426950408889634f;

    float qr0[4], qr1[4], m2[4], l[4], o0[4], o1[4];
    #pragma unroll
    for (int r = 0; r < 4; ++r) {
        const size_t rb = headbase + (size_t)(q0 + r) * DMODEL;
        qr0[r] = QO[rb + lane]      * qscale;
        qr1[r] = QO[rb + lane + 64] * qscale;
        m2[r] = -INFINITY;
        l[r] = 0.f; o0[r] = 0.f; o1[r] = 0.f;
    }

    const int jmax = q0 + 3;
    for (int j = 0; j <= jmax; ++j) {
        const size_t kb = headbase + (size_t)j * DMODEL;
        const float k0 = K[kb + lane];
        const float k1 = K[kb + lane + 64];
        const float v0 = V[kb + lane];
        const float v1 = V[kb + lane + 64];

        #pragma unroll
        for (int r = 0; r < 4; ++r) {
            float part = qr0[r] * k0 + qr1[r] * k1;
            #pragma unroll
            for (int off = 1; off < 64; off <<= 1)
                part += __shfl_xor(part, off, 64);
            // part is now lane-uniform -> all branches below are wave-uniform
            const int qi = q0 + r;
            if (j <= qi) {
                const float s2 = part + slope2 * (float)(j - qi);
                if (s2 > m2[r]) {
                    const float alpha = exp2f(m2[r] - s2);  // exp2(-inf)=0 first iter
                    m2[r] = s2;
                    l[r]  = l[r]  * alpha + 1.0f;
                    o0[r] = o0[r] * alpha + v0;
                    o1[r] = o1[r] * alpha + v1;
                } else {
                    const float p = exp2f(s2 - m2[r]);
                    l[r]  += p;
                    o0[r] += p * v0;
                    o1[r] += p * v1;
                }
            }
        }
    }

    #pragma unroll
    for (int r = 0; r < 4; ++r) {
        const float inv = 1.0f / l[r];
        const size_t rb = headbase + (size_t)(q0 + r) * DMODEL;
        QO[rb + lane]      = o0[r] * inv;
        QO[rb + lane + 64] = o1[r] * inv;
    }
}

// ---------------------------------------------------------------------------
extern "C" void kernel_launch(void* const* d_in, const int* in_sizes, int n_in,
                              void* d_out, int out_size, void* d_ws, size_t ws_size,
                              hipStream_t stream)
{
    const float* x  = (const float*)d_in[0];
    const float* wq = (const float*)d_in[1];
    const float* bq = (const float*)d_in[2];
    const float* wk = (const float*)d_in[3];
    const float* bk = (const float*)d_in[4];
    const float* wv = (const float*)d_in[5];
    const float* bv = (const float*)d_in[6];
    const float* wo = (const float*)d_in[7];
    const float* bo = (const float*)d_in[8];
    float* out = (float*)d_out;

    const size_t bufElems = (size_t)MROWS * DMODEL;   // 8.39M floats
    float* Q = (float*)d_ws;            // later overwritten with attention O
    float* Kb = Q + bufElems;
    float* Vb = Kb + bufElems;

    const dim3 gemmGrid(DMODEL / BN, MROWS / BM);     // (32, 64)
    const dim3 gemmBlock(256);

    gemm_bias_kernel<<<gemmGrid, gemmBlock, 0, stream>>>(x, wq, bq, Q,  MROWS, DMODEL, DMODEL);
    gemm_bias_kernel<<<gemmGrid, gemmBlock, 0, stream>>>(x, wk, bk, Kb, MROWS, DMODEL, DMODEL);
    gemm_bias_kernel<<<gemmGrid, gemmBlock, 0, stream>>>(x, wv, bv, Vb, MROWS, DMODEL, DMODEL);

    const dim3 attnGrid(SEQ / 16, NHEADS, BATCH);     // (128, 16, 2)
    attn_kernel<<<attnGrid, dim3(256), 0, stream>>>(Q, Kb, Vb);

    gemm_bias_kernel<<<gemmGrid, gemmBlock, 0, stream>>>(Q, wo, bo, out, MROWS, DMODEL, DMODEL);
}

// Round 2
// 2309.804 us; speedup vs baseline: 3.7682x; 3.7682x over previous
//
#include <hip/hip_runtime.h>
#include <hip/hip_bf16.h>
#include <math.h>

// Problem constants (fixed by reference)
#define BATCH 2
#define SEQ   2048
#define DMODEL 2048
#define NHEADS 16
#define HDIM  128
#define MROWS (BATCH * SEQ)   // 4096

typedef __attribute__((ext_vector_type(8))) short short8;
typedef __attribute__((ext_vector_type(8))) unsigned short ushort8;
typedef __attribute__((ext_vector_type(4))) float f32x4;

static __device__ __forceinline__ unsigned short f2bf(float x) {
    __hip_bfloat16 h = __float2bfloat16(x);
    return __builtin_bit_cast(unsigned short, h);
}

// ---------------------------------------------------------------------------
// GEMM: C[M,N] = A[M,K] @ W[K,N] + bias[N]   (fp32 compute, 64x64x16 tiles)
// BF16OUT=true writes bf16 (ushort) output, else fp32.
// ---------------------------------------------------------------------------
constexpr int BM = 64, BN = 64, BK = 16;

template <bool BF16OUT>
__global__ __launch_bounds__(256) void gemm_bias_kernel(
    const float* __restrict__ A, const float* __restrict__ W,
    const float* __restrict__ bias, void* __restrict__ Cv,
    int M, int N, int K)
{
    __shared__ __align__(16) float As[BK][BM + 4];
    __shared__ __align__(16) float Ws[BK][BN];

    const int tid = threadIdx.x;
    const int tx  = tid & 15;
    const int ty  = tid >> 4;
    const int bm  = blockIdx.y * BM;
    const int bn  = blockIdx.x * BN;

    const int a_row = tid >> 2;
    const int a_c4  = (tid & 3) << 2;
    const int w_row = tid >> 4;
    const int w_c4  = (tid & 15) << 2;

    float acc[4][4] = {};

    for (int k0 = 0; k0 < K; k0 += BK) {
        const float4 av = *(const float4*)(A + (size_t)(bm + a_row) * K + k0 + a_c4);
        As[a_c4 + 0][a_row] = av.x;
        As[a_c4 + 1][a_row] = av.y;
        As[a_c4 + 2][a_row] = av.z;
        As[a_c4 + 3][a_row] = av.w;
        *(float4*)(&Ws[w_row][w_c4]) =
            *(const float4*)(W + (size_t)(k0 + w_row) * N + bn + w_c4);
        __syncthreads();

        #pragma unroll
        for (int kk = 0; kk < BK; ++kk) {
            float a[4], w[4];
            #pragma unroll
            for (int i = 0; i < 4; ++i) a[i] = As[kk][ty * 4 + i];
            #pragma unroll
            for (int i = 0; i < 4; ++i) w[i] = Ws[kk][tx * 4 + i];
            #pragma unroll
            for (int i = 0; i < 4; ++i)
                #pragma unroll
                for (int j = 0; j < 4; ++j)
                    acc[i][j] += a[i] * w[j];
        }
        __syncthreads();
    }

    #pragma unroll
    for (int i = 0; i < 4; ++i) {
        const int row = bm + ty * 4 + i;
        const int col0 = bn + tx * 4;
        if constexpr (BF16OUT) {
            unsigned short* Cb = (unsigned short*)Cv;
            uint2 pk;
            pk.x = (unsigned)f2bf(acc[i][0] + bias[col0 + 0]) |
                   ((unsigned)f2bf(acc[i][1] + bias[col0 + 1]) << 16);
            pk.y = (unsigned)f2bf(acc[i][2] + bias[col0 + 2]) |
                   ((unsigned)f2bf(acc[i][3] + bias[col0 + 3]) << 16);
            *(uint2*)(&Cb[(size_t)row * N + col0]) = pk;
        } else {
            float* C = (float*)Cv;
            #pragma unroll
            for (int j = 0; j < 4; ++j)
                C[(size_t)row * N + col0 + j] = acc[i][j] + bias[col0 + j];
        }
    }
}

// ---------------------------------------------------------------------------
// MFMA flash attention w/ ALiBi + causal.
// Block = 256 threads = 4 waves; wave w owns 16 query rows (q0+16w..+15).
// Key loop: 32-key tiles staged in LDS (K row-major, V transposed).
// mfma_f32_16x16x32_bf16 layouts:
//   A-frag: m=lane&15, k=quad*8+j ; B-frag: n=lane&15, k=quad*8+j (B^T rows)
//   C/D:    col=lane&15, row=quad*4+reg
// ---------------------------------------------------------------------------
#define KS_STRIDE 136   // 32 rows x 128 dims, pad 128->136 (16B-aligned, 2-way banks)
#define VT_STRIDE 40    // 128 dims x 32 keys, pad 32->40
#define P_STRIDE  40    // per-wave 16 x 32 P tile, pad 32->40

__global__ __launch_bounds__(256) void attn_kernel(
    const unsigned short* __restrict__ Qb, const unsigned short* __restrict__ Kb,
    const unsigned short* __restrict__ Vb, float* __restrict__ O)
{
    __shared__ __align__(16) unsigned short Ks[32 * KS_STRIDE];
    __shared__ __align__(16) unsigned short Vt[128 * VT_STRIDE];
    __shared__ __align__(16) unsigned short Pl[4 * 16 * P_STRIDE];

    const int tid  = threadIdx.x;
    const int lane = tid & 63;
    const int wave = tid >> 6;
    const int ln15 = lane & 15;
    const int quad = lane >> 4;
    const int h = blockIdx.y;
    const int b = blockIdx.z;
    const int q0  = blockIdx.x * 64;
    const int q0w = q0 + wave * 16;

    const size_t rowbase = (size_t)b * SEQ;
    const size_t hoff    = (size_t)h * HDIM;

    // (1/sqrt(128)) * log2(e); ALiBi slope_h * log2(e)
    const float sc2    = 0.08838834764831845f * 1.4426950408889634f;
    const float slope2 = exp2f(-0.5f * (float)(h + 1)) * 1.4426950408889634f;

    // Q fragments (A-layout), 4 k-chunks of 32
    short8 qf[4];
    {
        const unsigned short* qp =
            Qb + (rowbase + q0w + ln15) * DMODEL + hoff + quad * 8;
        qf[0] = *(const short8*)(qp);
        qf[1] = *(const short8*)(qp + 32);
        qf[2] = *(const short8*)(qp + 64);
        qf[3] = *(const short8*)(qp + 96);
    }

    f32x4 acc[8];
    #pragma unroll
    for (int nt = 0; nt < 8; ++nt) acc[nt] = (f32x4){0.f, 0.f, 0.f, 0.f};
    float m2[4], lsum[4];
    #pragma unroll
    for (int r = 0; r < 4; ++r) { m2[r] = -30000.0f; lsum[r] = 0.f; }

    // staging assignments
    const int krow = tid >> 3;           // 0..31
    const int kcol = (tid & 7) * 16;     // 0..112
    const int vdim = tid & 127;          // 0..127
    const int vkp  = (tid >> 7) * 2;     // 0 or 2

    const int nTiles = 2 * blockIdx.x + 2;   // covers keys 0..q0+63

    for (int t = 0; t < nTiles; ++t) {
        const int kb = t * 32;
        __syncthreads();   // previous tile's compute done before overwrite
        // ---- stage K tile (32 x 128, row-major) ----
        {
            const unsigned short* kp =
                Kb + (rowbase + kb + krow) * DMODEL + hoff + kcol;
            ushort8 u0 = *(const ushort8*)(kp);
            ushort8 u1 = *(const ushort8*)(kp + 8);
            *(ushort8*)(&Ks[krow * KS_STRIDE + kcol])     = u0;
            *(ushort8*)(&Ks[krow * KS_STRIDE + kcol + 8]) = u1;
        }
        // ---- stage V^T tile (128 dims x 32 keys) ----
        #pragma unroll
        for (int kp8 = 0; kp8 < 8; ++kp8) {
            const int key0 = kp8 * 4 + vkp;
            const unsigned short* vp =
                Vb + (rowbase + kb + key0) * DMODEL + hoff + vdim;
            unsigned int w = (unsigned int)vp[0] | ((unsigned int)vp[DMODEL] << 16);
            *(unsigned int*)(&Vt[vdim * VT_STRIDE + key0]) = w;
        }
        __syncthreads();

        if (kb > q0w + 15) continue;   // whole tile masked for this wave

        // ---- S = Q K^T, two 16-key subtiles ----
        f32x4 s0 = (f32x4){0.f,0.f,0.f,0.f}, s1 = (f32x4){0.f,0.f,0.f,0.f};
        #pragma unroll
        for (int c = 0; c < 4; ++c) {
            short8 kf0 = *(const short8*)(&Ks[ln15 * KS_STRIDE + c * 32 + quad * 8]);
            short8 kf1 = *(const short8*)(&Ks[(16 + ln15) * KS_STRIDE + c * 32 + quad * 8]);
            s0 = __builtin_amdgcn_mfma_f32_16x16x32_bf16(qf[c], kf0, s0, 0, 0, 0);
            s1 = __builtin_amdgcn_mfma_f32_16x16x32_bf16(qf[c], kf1, s1, 0, 0, 0);
        }

        // ---- scores + online softmax (log2 domain) ----
        float p0[4], p1[4], alpha[4];
        #pragma unroll
        for (int r = 0; r < 4; ++r) {
            const int qrow = q0w + quad * 4 + r;
            const int k0i = kb + ln15;
            const int k1i = kb + 16 + ln15;
            float v0 = (k0i <= qrow) ? (s0[r] * sc2 + slope2 * (float)(k0i - qrow)) : -1e30f;
            float v1 = (k1i <= qrow) ? (s1[r] * sc2 + slope2 * (float)(k1i - qrow)) : -1e30f;
            float mx = fmaxf(v0, v1);
            mx = fmaxf(mx, __shfl_xor(mx, 1, 64));
            mx = fmaxf(mx, __shfl_xor(mx, 2, 64));
            mx = fmaxf(mx, __shfl_xor(mx, 4, 64));
            mx = fmaxf(mx, __shfl_xor(mx, 8, 64));
            const float mnew = fmaxf(m2[r], mx);
            alpha[r] = exp2f(m2[r] - mnew);
            m2[r] = mnew;
            p0[r] = exp2f(v0 - mnew);
            p1[r] = exp2f(v1 - mnew);
            lsum[r] = lsum[r] * alpha[r] + p0[r] + p1[r];
        }
        #pragma unroll
        for (int nt = 0; nt < 8; ++nt)
            #pragma unroll
            for (int r = 0; r < 4; ++r) acc[nt][r] *= alpha[r];

        // ---- P (C-layout) -> LDS -> A-layout bf16 ----
        unsigned short* Pw = &Pl[wave * 16 * P_STRIDE];
        #pragma unroll
        for (int r = 0; r < 4; ++r) {
            unsigned int w0 = f2bf(p0[r]);
            unsigned int w1 = f2bf(p1[r]);
            unsigned int n0 = (unsigned int)__shfl_xor((int)w0, 1, 64);
            unsigned int n1 = (unsigned int)__shfl_xor((int)w1, 1, 64);
            if (!(ln15 & 1)) {
                *(unsigned int*)(&Pw[(quad * 4 + r) * P_STRIDE + ln15])      = w0 | (n0 << 16);
                *(unsigned int*)(&Pw[(quad * 4 + r) * P_STRIDE + 16 + ln15]) = w1 | (n1 << 16);
            }
        }
        __builtin_amdgcn_s_waitcnt(0xC07F);   // lgkmcnt(0): P writes visible in-wave
        short8 pf = *(const short8*)(&Pw[ln15 * P_STRIDE + quad * 8]);

        // ---- O += P V ----
        #pragma unroll
        for (int nt = 0; nt < 8; ++nt) {
            short8 vf = *(const short8*)(&Vt[(nt * 16 + ln15) * VT_STRIDE + quad * 8]);
            acc[nt] = __builtin_amdgcn_mfma_f32_16x16x32_bf16(pf, vf, acc[nt], 0, 0, 0);
        }
    }

    // ---- finalize: reduce l across the 16 lanes of each row, store O ----
    #pragma unroll
    for (int r = 0; r < 4; ++r) {
        float l = lsum[r];
        l += __shfl_xor(l, 1, 64);
        l += __shfl_xor(l, 2, 64);
        l += __shfl_xor(l, 4, 64);
        l += __shfl_xor(l, 8, 64);
        const float inv = 1.0f / l;
        const size_t ob = (rowbase + q0w + quad * 4 + r) * DMODEL + hoff;
        #pragma unroll
        for (int nt = 0; nt < 8; ++nt)
            O[ob + nt * 16 + ln15] = acc[nt][r] * inv;
    }
}

// ---------------------------------------------------------------------------
extern "C" void kernel_launch(void* const* d_in, const int* in_sizes, int n_in,
                              void* d_out, int out_size, void* d_ws, size_t ws_size,
                              hipStream_t stream)
{
    const float* x  = (const float*)d_in[0];
    const float* wq = (const float*)d_in[1];
    const float* bq = (const float*)d_in[2];
    const float* wk = (const float*)d_in[3];
    const float* bk = (const float*)d_in[4];
    const float* wv = (const float*)d_in[5];
    const float* bv = (const float*)d_in[6];
    const float* wo = (const float*)d_in[7];
    const float* bo = (const float*)d_in[8];
    float* out = (float*)d_out;

    const size_t bufElems = (size_t)MROWS * DMODEL;
    unsigned short* Qb = (unsigned short*)d_ws;       // bf16 Q
    unsigned short* Kb = Qb + bufElems;               // bf16 K
    unsigned short* Vb = Kb + bufElems;               // bf16 V
    float* O = (float*)(Vb + bufElems);               // fp32 attention output

    const dim3 gemmGrid(DMODEL / BN, MROWS / BM);
    const dim3 gemmBlock(256);

    gemm_bias_kernel<true><<<gemmGrid, gemmBlock, 0, stream>>>(x, wq, bq, Qb, MROWS, DMODEL, DMODEL);
    gemm_bias_kernel<true><<<gemmGrid, gemmBlock, 0, stream>>>(x, wk, bk, Kb, MROWS, DMODEL, DMODEL);
    gemm_bias_kernel<true><<<gemmGrid, gemmBlock, 0, stream>>>(x, wv, bv, Vb, MROWS, DMODEL, DMODEL);

    const dim3 attnGrid(SEQ / 64, NHEADS, BATCH);
    attn_kernel<<<attnGrid, dim3(256), 0, stream>>>(Qb, Kb, Vb, O);

    gemm_bias_kernel<false><<<gemmGrid, gemmBlock, 0, stream>>>(O, wo, bo, out, MROWS, DMODEL, DMODEL);
}

// Round 3
// 641.127 us; speedup vs baseline: 13.5759x; 3.6027x over previous
//
#include <hip/hip_runtime.h>
#include <hip/hip_bf16.h>
#include <math.h>

// Problem constants (fixed by reference)
#define BATCH 2
#define SEQ   2048
#define DMODEL 2048
#define NHEADS 16
#define HDIM  128
#define MROWS (BATCH * SEQ)   // 4096

typedef __attribute__((ext_vector_type(8))) short short8;
typedef __attribute__((ext_vector_type(8))) unsigned short ushort8;
typedef __attribute__((ext_vector_type(4))) float f32x4;

static __device__ __forceinline__ unsigned short f2bf(float x) {
    __hip_bfloat16 h = __float2bfloat16(x);
    return __builtin_bit_cast(unsigned short, h);
}

static __device__ __forceinline__ void async_load16(const void* g, void* l) {
    __builtin_amdgcn_global_load_lds(
        (const __attribute__((address_space(1))) unsigned int*)g,
        (__attribute__((address_space(3))) unsigned int*)l, 16, 0, 0);
}

// ---------------------------------------------------------------------------
// fp32 -> bf16 elementwise convert (x)
// ---------------------------------------------------------------------------
__global__ __launch_bounds__(256) void convert_bf16_kernel(
    const float* __restrict__ in, unsigned short* __restrict__ out, int n)
{
    const int idx = (blockIdx.x * 256 + threadIdx.x) * 4;
    if (idx < n) {
        const float4 v = *(const float4*)(in + idx);
        ushort4 u;
        u.x = f2bf(v.x); u.y = f2bf(v.y); u.z = f2bf(v.z); u.w = f2bf(v.w);
        *(ushort4*)(out + idx) = u;
    }
}

// ---------------------------------------------------------------------------
// W [K,N] fp32 -> W^T [N,K] bf16, 64x64 LDS-tiled transpose
// ---------------------------------------------------------------------------
__global__ __launch_bounds__(256) void transpose_bf16_kernel(
    const float* __restrict__ W, unsigned short* __restrict__ Wt, int K, int N)
{
    __shared__ float T[64][65];
    const int tid = threadIdx.x;
    const int tr  = tid >> 4;          // 0..15
    const int tc4 = (tid & 15) * 4;    // 0..60
    const int k0 = blockIdx.y * 64;
    const int n0 = blockIdx.x * 64;

    #pragma unroll
    for (int i = 0; i < 4; ++i) {
        const int kr = i * 16 + tr;
        const float4 v = *(const float4*)(W + (size_t)(k0 + kr) * N + n0 + tc4);
        T[kr][tc4 + 0] = v.x; T[kr][tc4 + 1] = v.y;
        T[kr][tc4 + 2] = v.z; T[kr][tc4 + 3] = v.w;
    }
    __syncthreads();
    #pragma unroll
    for (int i = 0; i < 4; ++i) {
        const int nr = i * 16 + tr;
        ushort4 u;
        u.x = f2bf(T[tc4 + 0][nr]); u.y = f2bf(T[tc4 + 1][nr]);
        u.z = f2bf(T[tc4 + 2][nr]); u.w = f2bf(T[tc4 + 3][nr]);
        *(ushort4*)(Wt + (size_t)(n0 + nr) * K + k0 + tc4) = u;
    }
}

// ---------------------------------------------------------------------------
// MFMA GEMM (m97 structure): C[M,N] = A[M,K] @ Bt[N,K]^T + bias
// A, Bt bf16 row-major. 128x128 tile, BK=32, 256 thr = 4 waves (2x2 of 64x64),
// global_load_lds width-16 staging (wave-uniform base + lane*16, unpadded).
// mfma_f32_16x16x32_bf16: A m=lane&15,k=quad*8+j ; B n=lane&15,k=quad*8+j ;
// C/D col=lane&15,row=quad*4+reg.
// ---------------------------------------------------------------------------
template <bool BF16OUT>
__global__ __launch_bounds__(256) void gemm_mfma_kernel(
    const unsigned short* __restrict__ A, const unsigned short* __restrict__ Bt,
    const float* __restrict__ bias, void* __restrict__ Cv,
    int M, int N, int K)
{
    __shared__ __align__(16) unsigned short As[128 * 32];  // [row][k] contiguous
    __shared__ __align__(16) unsigned short Bs[128 * 32];  // [n][k] contiguous

    const int tid  = threadIdx.x;
    const int lane = tid & 63;
    const int wave = tid >> 6;
    const int ln15 = lane & 15;
    const int quad = lane >> 4;
    const int wm = (wave & 1) * 64;
    const int wn = (wave >> 1) * 64;
    const int bm = blockIdx.y * 128;
    const int bn = blockIdx.x * 128;

    // staging: thread t covers elements t*8..t*8+7 of each 64-row half-tile
    const int srow = tid >> 2;        // 0..63
    const int scol = (tid & 3) * 8;   // 0,8,16,24

    const unsigned short* Ap = A  + (size_t)(bm + srow) * K + scol;
    const unsigned short* Bp = Bt + (size_t)(bn + srow) * K + scol;

    f32x4 acc[4][4];
    #pragma unroll
    for (int i = 0; i < 4; ++i)
        #pragma unroll
        for (int j = 0; j < 4; ++j) acc[i][j] = (f32x4){0.f, 0.f, 0.f, 0.f};

    for (int k0 = 0; k0 < K; k0 += 32) {
        __syncthreads();
        async_load16(Ap + k0,                    As + wave * 512);
        async_load16(Ap + (size_t)64 * K + k0,   As + 2048 + wave * 512);
        async_load16(Bp + k0,                    Bs + wave * 512);
        async_load16(Bp + (size_t)64 * K + k0,   Bs + 2048 + wave * 512);
        __syncthreads();

        short8 af[4], bf[4];
        #pragma unroll
        for (int mt = 0; mt < 4; ++mt)
            af[mt] = *(const short8*)(&As[(wm + mt * 16 + ln15) * 32 + quad * 8]);
        #pragma unroll
        for (int nt = 0; nt < 4; ++nt)
            bf[nt] = *(const short8*)(&Bs[(wn + nt * 16 + ln15) * 32 + quad * 8]);
        #pragma unroll
        for (int mt = 0; mt < 4; ++mt)
            #pragma unroll
            for (int nt = 0; nt < 4; ++nt)
                acc[mt][nt] = __builtin_amdgcn_mfma_f32_16x16x32_bf16(
                    af[mt], bf[nt], acc[mt][nt], 0, 0, 0);
    }

    #pragma unroll
    for (int mt = 0; mt < 4; ++mt) {
        #pragma unroll
        for (int r = 0; r < 4; ++r) {
            const int row = bm + wm + mt * 16 + quad * 4 + r;
            #pragma unroll
            for (int nt = 0; nt < 4; ++nt) {
                const int col = bn + wn + nt * 16 + ln15;
                const float v = acc[mt][nt][r] + bias[col];
                if constexpr (BF16OUT)
                    ((unsigned short*)Cv)[(size_t)row * N + col] = f2bf(v);
                else
                    ((float*)Cv)[(size_t)row * N + col] = v;
            }
        }
    }
}

// ---------------------------------------------------------------------------
// MFMA flash attention w/ ALiBi + causal (same as R1, bf16 output).
// ---------------------------------------------------------------------------
#define KS_STRIDE 136
#define VT_STRIDE 40
#define P_STRIDE  40

__global__ __launch_bounds__(256) void attn_kernel(
    const unsigned short* __restrict__ Qb, const unsigned short* __restrict__ Kb,
    const unsigned short* __restrict__ Vb, unsigned short* __restrict__ O)
{
    __shared__ __align__(16) unsigned short Ks[32 * KS_STRIDE];
    __shared__ __align__(16) unsigned short Vt[128 * VT_STRIDE];
    __shared__ __align__(16) unsigned short Pl[4 * 16 * P_STRIDE];

    const int tid  = threadIdx.x;
    const int lane = tid & 63;
    const int wave = tid >> 6;
    const int ln15 = lane & 15;
    const int quad = lane >> 4;
    const int h = blockIdx.y;
    const int b = blockIdx.z;
    const int q0  = blockIdx.x * 64;
    const int q0w = q0 + wave * 16;

    const size_t rowbase = (size_t)b * SEQ;
    const size_t hoff    = (size_t)h * HDIM;

    const float sc2    = 0.08838834764831845f * 1.4426950408889634f;
    const float slope2 = exp2f(-0.5f * (float)(h + 1)) * 1.4426950408889634f;

    short8 qf[4];
    {
        const unsigned short* qp =
            Qb + (rowbase + q0w + ln15) * DMODEL + hoff + quad * 8;
        qf[0] = *(const short8*)(qp);
        qf[1] = *(const short8*)(qp + 32);
        qf[2] = *(const short8*)(qp + 64);
        qf[3] = *(const short8*)(qp + 96);
    }

    f32x4 acc[8];
    #pragma unroll
    for (int nt = 0; nt < 8; ++nt) acc[nt] = (f32x4){0.f, 0.f, 0.f, 0.f};
    float m2[4], lsum[4];
    #pragma unroll
    for (int r = 0; r < 4; ++r) { m2[r] = -30000.0f; lsum[r] = 0.f; }

    const int krow = tid >> 3;
    const int kcol = (tid & 7) * 16;
    const int vdim = tid & 127;
    const int vkp  = (tid >> 7) * 2;

    const int nTiles = 2 * blockIdx.x + 2;

    for (int t = 0; t < nTiles; ++t) {
        const int kb = t * 32;
        __syncthreads();
        {
            const unsigned short* kp =
                Kb + (rowbase + kb + krow) * DMODEL + hoff + kcol;
            ushort8 u0 = *(const ushort8*)(kp);
            ushort8 u1 = *(const ushort8*)(kp + 8);
            *(ushort8*)(&Ks[krow * KS_STRIDE + kcol])     = u0;
            *(ushort8*)(&Ks[krow * KS_STRIDE + kcol + 8]) = u1;
        }
        #pragma unroll
        for (int kp8 = 0; kp8 < 8; ++kp8) {
            const int key0 = kp8 * 4 + vkp;
            const unsigned short* vp =
                Vb + (rowbase + kb + key0) * DMODEL + hoff + vdim;
            unsigned int w = (unsigned int)vp[0] | ((unsigned int)vp[DMODEL] << 16);
            *(unsigned int*)(&Vt[vdim * VT_STRIDE + key0]) = w;
        }
        __syncthreads();

        if (kb > q0w + 15) continue;

        f32x4 s0 = (f32x4){0.f,0.f,0.f,0.f}, s1 = (f32x4){0.f,0.f,0.f,0.f};
        #pragma unroll
        for (int c = 0; c < 4; ++c) {
            short8 kf0 = *(const short8*)(&Ks[ln15 * KS_STRIDE + c * 32 + quad * 8]);
            short8 kf1 = *(const short8*)(&Ks[(16 + ln15) * KS_STRIDE + c * 32 + quad * 8]);
            s0 = __builtin_amdgcn_mfma_f32_16x16x32_bf16(qf[c], kf0, s0, 0, 0, 0);
            s1 = __builtin_amdgcn_mfma_f32_16x16x32_bf16(qf[c], kf1, s1, 0, 0, 0);
        }

        float p0[4], p1[4], alpha[4];
        #pragma unroll
        for (int r = 0; r < 4; ++r) {
            const int qrow = q0w + quad * 4 + r;
            const int k0i = kb + ln15;
            const int k1i = kb + 16 + ln15;
            float v0 = (k0i <= qrow) ? (s0[r] * sc2 + slope2 * (float)(k0i - qrow)) : -1e30f;
            float v1 = (k1i <= qrow) ? (s1[r] * sc2 + slope2 * (float)(k1i - qrow)) : -1e30f;
            float mx = fmaxf(v0, v1);
            mx = fmaxf(mx, __shfl_xor(mx, 1, 64));
            mx = fmaxf(mx, __shfl_xor(mx, 2, 64));
            mx = fmaxf(mx, __shfl_xor(mx, 4, 64));
            mx = fmaxf(mx, __shfl_xor(mx, 8, 64));
            const float mnew = fmaxf(m2[r], mx);
            alpha[r] = exp2f(m2[r] - mnew);
            m2[r] = mnew;
            p0[r] = exp2f(v0 - mnew);
            p1[r] = exp2f(v1 - mnew);
            lsum[r] = lsum[r] * alpha[r] + p0[r] + p1[r];
        }
        #pragma unroll
        for (int nt = 0; nt < 8; ++nt)
            #pragma unroll
            for (int r = 0; r < 4; ++r) acc[nt][r] *= alpha[r];

        unsigned short* Pw = &Pl[wave * 16 * P_STRIDE];
        #pragma unroll
        for (int r = 0; r < 4; ++r) {
            unsigned int w0 = f2bf(p0[r]);
            unsigned int w1 = f2bf(p1[r]);
            unsigned int n0 = (unsigned int)__shfl_xor((int)w0, 1, 64);
            unsigned int n1 = (unsigned int)__shfl_xor((int)w1, 1, 64);
            if (!(ln15 & 1)) {
                *(unsigned int*)(&Pw[(quad * 4 + r) * P_STRIDE + ln15])      = w0 | (n0 << 16);
                *(unsigned int*)(&Pw[(quad * 4 + r) * P_STRIDE + 16 + ln15]) = w1 | (n1 << 16);
            }
        }
        __builtin_amdgcn_s_waitcnt(0xC07F);
        short8 pf = *(const short8*)(&Pw[ln15 * P_STRIDE + quad * 8]);

        #pragma unroll
        for (int nt = 0; nt < 8; ++nt) {
            short8 vf = *(const short8*)(&Vt[(nt * 16 + ln15) * VT_STRIDE + quad * 8]);
            acc[nt] = __builtin_amdgcn_mfma_f32_16x16x32_bf16(pf, vf, acc[nt], 0, 0, 0);
        }
    }

    #pragma unroll
    for (int r = 0; r < 4; ++r) {
        float l = lsum[r];
        l += __shfl_xor(l, 1, 64);
        l += __shfl_xor(l, 2, 64);
        l += __shfl_xor(l, 4, 64);
        l += __shfl_xor(l, 8, 64);
        const float inv = 1.0f / l;
        const size_t ob = (rowbase + q0w + quad * 4 + r) * DMODEL + hoff;
        #pragma unroll
        for (int nt = 0; nt < 8; ++nt)
            O[ob + nt * 16 + ln15] = f2bf(acc[nt][r] * inv);
    }
}

// ---------------------------------------------------------------------------
extern "C" void kernel_launch(void* const* d_in, const int* in_sizes, int n_in,
                              void* d_out, int out_size, void* d_ws, size_t ws_size,
                              hipStream_t stream)
{
    const float* x  = (const float*)d_in[0];
    const float* wq = (const float*)d_in[1];
    const float* bq = (const float*)d_in[2];
    const float* wk = (const float*)d_in[3];
    const float* bk = (const float*)d_in[4];
    const float* wv = (const float*)d_in[5];
    const float* bv = (const float*)d_in[6];
    const float* wo = (const float*)d_in[7];
    const float* bo = (const float*)d_in[8];
    float* out = (float*)d_out;

    const size_t bufElems = (size_t)MROWS * DMODEL;   // 8.39M
    unsigned short* Qb = (unsigned short*)d_ws;
    unsigned short* Kb = Qb + bufElems;
    unsigned short* Vb = Kb + bufElems;
    unsigned short* Ob = Vb + bufElems;
    unsigned short* xb = Ob + bufElems;
    unsigned short* Wt = xb + bufElems;   // 2048*2048, reused per weight

    const dim3 cvtGrid((int)(bufElems / 1024));
    const dim3 trGrid(DMODEL / 64, DMODEL / 64);
    const dim3 gemmGrid(DMODEL / 128, MROWS / 128);   // (16, 32)
    const dim3 blk(256);

    convert_bf16_kernel<<<cvtGrid, blk, 0, stream>>>(x, xb, (int)bufElems);

    transpose_bf16_kernel<<<trGrid, blk, 0, stream>>>(wq, Wt, DMODEL, DMODEL);
    gemm_mfma_kernel<true><<<gemmGrid, blk, 0, stream>>>(xb, Wt, bq, Qb, MROWS, DMODEL, DMODEL);
    transpose_bf16_kernel<<<trGrid, blk, 0, stream>>>(wk, Wt, DMODEL, DMODEL);
    gemm_mfma_kernel<true><<<gemmGrid, blk, 0, stream>>>(xb, Wt, bk, Kb, MROWS, DMODEL, DMODEL);
    transpose_bf16_kernel<<<trGrid, blk, 0, stream>>>(wv, Wt, DMODEL, DMODEL);
    gemm_mfma_kernel<true><<<gemmGrid, blk, 0, stream>>>(xb, Wt, bv, Vb, MROWS, DMODEL, DMODEL);

    const dim3 attnGrid(SEQ / 64, NHEADS, BATCH);
    attn_kernel<<<attnGrid, blk, 0, stream>>>(Qb, Kb, Vb, Ob);

    transpose_bf16_kernel<<<trGrid, blk, 0, stream>>>(wo, Wt, DMODEL, DMODEL);
    gemm_mfma_kernel<false><<<gemmGrid, blk, 0, stream>>>(Ob, Wt, bo, out, MROWS, DMODEL, DMODEL);
}